// Round 6
// baseline (249.920 us; speedup 1.0000x reference)
//
#include <hip/hip_runtime.h>

typedef __attribute__((ext_vector_type(8))) unsigned short ushort8;
typedef __attribute__((ext_vector_type(8))) short short8;
typedef __attribute__((ext_vector_type(4))) float f32x4;

#define M_DIM 8192
#define N_DIM 2048
#define K_DIM 2048
#define BM 256
#define BN 256
#define BK 64
#define KITER (K_DIM / BK)   // 32

// ---- fp32 -> bf16 (RNE) ----
__device__ __forceinline__ unsigned short f32_to_bf16(float f) {
  unsigned int u = __float_as_uint(f);
  u += 0x7fffu + ((u >> 16) & 1u);
  return (unsigned short)(u >> 16);
}

__global__ void __launch_bounds__(256) cast_both_x8(
    const float* __restrict__ x, const float* __restrict__ W,
    unsigned short* __restrict__ xb, unsigned short* __restrict__ Wb) {
  const long nx = (long)M_DIM * K_DIM;
  long i = ((long)blockIdx.x * 256 + threadIdx.x) * 8;
  const float* s;
  unsigned short* d;
  if (i < nx) { s = x + i; d = xb + i; }
  else        { s = W + (i - nx); d = Wb + (i - nx); }
  float4 a = *(const float4*)(s);
  float4 b = *(const float4*)(s + 4);
  ushort8 r;
  r[0] = f32_to_bf16(a.x); r[1] = f32_to_bf16(a.y);
  r[2] = f32_to_bf16(a.z); r[3] = f32_to_bf16(a.w);
  r[4] = f32_to_bf16(b.x); r[5] = f32_to_bf16(b.y);
  r[6] = f32_to_bf16(b.z); r[7] = f32_to_bf16(b.w);
  *(ushort8*)(d) = r;
}

__device__ __forceinline__ void gload_lds16(const unsigned short* g, unsigned short* l) {
  __builtin_amdgcn_global_load_lds(
      (const __attribute__((address_space(1))) void*)g,
      (__attribute__((address_space(3))) void*)l,
      16, 0, 0);
}

// Fat-tile GEMM: C = A(MxK)*B(NxK)^T + bias.
// 256x256 block tile, 4 waves, each wave owns a 128x128 sub-tile
// (8x8 16x16x32 MFMA frags, 256 acc regs). Intensity 64 FLOP/LDS-byte
// -> MFMA-bound instead of LDS-BW-bound (the R4/R5 84us ceiling).
// Double-buffered LDS (2 x 64 KB): DMA for iter k+1 issued BEFORE compute
// of iter k, so the barrier's vmcnt(0) drain hits already-landed loads.
// LDS image per buffer: chunk p (16B) at p*16, holds k-chunk (p&7)^(row&7)
// of row p>>3 (XOR swizzle: conflict-free for 16-row frag reads).
__global__ void __launch_bounds__(256, 1) gemm_fat(
    const unsigned short* __restrict__ A,
    const unsigned short* __restrict__ B,
    const float* __restrict__ bias,
    float* __restrict__ C) {
  __shared__ unsigned short lds[2 * 2 * 16384];  // [buf][A|B][16384] = 128 KB

  const int tid  = threadIdx.x;
  const int lane = tid & 63;
  const int wave = tid >> 6;
  const int wm = wave & 1;
  const int wn = wave >> 1;

  // 1 block/CU, 256 blocks. bn = L&7 -> all 32 blocks on an XCD share one
  // B panel (hot in 4MB L2); A panels stream via LLC.
  const int L = blockIdx.x;
  const int bm0 = (L >> 3) * BM;
  const int bn0 = (L & 7) * BN;

  // staging: 2048 16B-chunks per matrix per buffer; thread t does p=t+256*j
  int rc[8], ldo[8];
#pragma unroll
  for (int j = 0; j < 8; ++j) {
    int p = tid + 256 * j;
    int r = p >> 3;
    int cb = (p & 7) ^ (r & 7);
    rc[j]  = r * K_DIM + cb * 8;
    ldo[j] = p * 8;
  }
  const unsigned short* Ab = A + (size_t)bm0 * K_DIM;
  const unsigned short* Bb = B + (size_t)bn0 * K_DIM;

  auto stage = [&](int k0, int buf) {
    unsigned short* sa = lds + buf * 32768;
    unsigned short* sb = sa + 16384;
#pragma unroll
    for (int j = 0; j < 8; ++j) gload_lds16(Ab + rc[j] + k0, sa + ldo[j]);
#pragma unroll
    for (int j = 0; j < 8; ++j) gload_lds16(Bb + rc[j] + k0, sb + ldo[j]);
  };

  // fragment LDS offsets: A[m=lane&15][k=(lane>>4)*8+j], substep s adds 32
  const int frow = lane & 15;
  const int q    = lane >> 4;
  int aoff[8][2], boff[8][2];
#pragma unroll
  for (int mi = 0; mi < 8; ++mi) {
    int rr = wm * 128 + mi * 16 + frow;
    int rb = rr & 7;
#pragma unroll
    for (int s = 0; s < 2; ++s) {
      int cb = s * 4 + q;
      aoff[mi][s] = (rr * 8 + (cb ^ rb)) * 8;
    }
  }
#pragma unroll
  for (int ni = 0; ni < 8; ++ni) {
    int rr = wn * 128 + ni * 16 + frow;
    int rb = rr & 7;
#pragma unroll
    for (int s = 0; s < 2; ++s) {
      int cb = s * 4 + q;
      boff[ni][s] = (rr * 8 + (cb ^ rb)) * 8;
    }
  }

  f32x4 acc[8][8] = {};

  stage(0, 0);
  __syncthreads();

  for (int it = 0; it < KITER; ++it) {
    const int cur = it & 1;
    if (it + 1 < KITER) stage((it + 1) * BK, cur ^ 1);  // async, lands during compute
    const unsigned short* sa = lds + cur * 32768;
    const unsigned short* sb = sa + 16384;
#pragma unroll
    for (int s = 0; s < 2; ++s) {
      short8 af[8], bf[8];
#pragma unroll
      for (int mi = 0; mi < 8; ++mi) af[mi] = *(const short8*)(sa + aoff[mi][s]);
#pragma unroll
      for (int ni = 0; ni < 8; ++ni) bf[ni] = *(const short8*)(sb + boff[ni][s]);
#pragma unroll
      for (int mi = 0; mi < 8; ++mi)
#pragma unroll
        for (int ni = 0; ni < 8; ++ni)
          acc[mi][ni] = __builtin_amdgcn_mfma_f32_16x16x32_bf16(
              af[mi], bf[ni], acc[mi][ni], 0, 0, 0);
    }
    __syncthreads();  // vmcnt(0) drains loads issued ~2400 cyc ago: cheap
  }

  // epilogue: C/D layout col=lane&15, row=(lane>>4)*4+reg
  const int col16 = lane & 15;
  const int row4  = (lane >> 4) * 4;
#pragma unroll
  for (int ni = 0; ni < 8; ++ni) {
    int gcol = bn0 + wn * 128 + ni * 16 + col16;
    float bv = bias[gcol];
#pragma unroll
    for (int mi = 0; mi < 8; ++mi) {
      int grow = bm0 + wm * 128 + mi * 16 + row4;
#pragma unroll
      for (int r = 0; r < 4; ++r)
        C[(size_t)(grow + r) * N_DIM + gcol] = acc[mi][ni][r] + bv;
    }
  }
}

extern "C" void kernel_launch(void* const* d_in, const int* in_sizes, int n_in,
                              void* d_out, int out_size, void* d_ws, size_t ws_size,
                              hipStream_t stream) {
  const float* x = (const float*)d_in[0];
  const float* W = (const float*)d_in[1];
  const float* b = (const float*)d_in[2];
  float* out = (float*)d_out;

  unsigned short* xb = (unsigned short*)d_ws;
  unsigned short* Wb = xb + (size_t)M_DIM * K_DIM;

  const long ntot = (long)M_DIM * K_DIM + (long)N_DIM * K_DIM;
  cast_both_x8<<<(int)(ntot / (256 * 8)), 256, 0, stream>>>(x, W, xb, Wb);

  gemm_fat<<<(M_DIM / BM) * (N_DIM / BN), 256, 0, stream>>>(xb, Wb, b, out);
}